// Round 4
// baseline (116.617 us; speedup 1.0000x reference)
//
#include <hip/hip_runtime.h>
#include <hip/hip_bf16.h>
#include <math.h>

#define BS 8
#define NN 1024
#define FIN 256
#define HEADS 8
#define FO 64
#define NH (HEADS*FO)   /* 512 */
static constexpr float ALPHA = 0.2f;

typedef short bf16x8 __attribute__((ext_vector_type(8)));
typedef float f32x4  __attribute__((ext_vector_type(4)));
typedef unsigned short u16;
typedef unsigned u32;
typedef u16 u16x4v __attribute__((ext_vector_type(4)));
typedef u16 u16x8v __attribute__((ext_vector_type(8)));

__device__ __forceinline__ u16 f2b(float x) {
    __hip_bfloat16 b = __float2bfloat16(x);
    return *reinterpret_cast<u16*>(&b);
}
__device__ __forceinline__ void gload_lds16(const void* g, void* l) {
    __builtin_amdgcn_global_load_lds(
        (const __attribute__((address_space(1))) unsigned int*)g,
        (__attribute__((address_space(3))) unsigned int*)l, 16, 0, 0);
}

// ---------------------------------------------------------------------------
// cvt_h: h f32 -> bf16
// ---------------------------------------------------------------------------
__global__ __launch_bounds__(256) void cvt_h(const float* __restrict__ h,
                                             u16* __restrict__ hb) {
    const int i = (blockIdx.x * 256 + threadIdx.x) * 8;
    const float4 v0 = *reinterpret_cast<const float4*>(h + i);
    const float4 v1 = *reinterpret_cast<const float4*>(h + i + 4);
    u16x8v o;
    o[0]=f2b(v0.x); o[1]=f2b(v0.y); o[2]=f2b(v0.z); o[3]=f2b(v0.w);
    o[4]=f2b(v1.x); o[5]=f2b(v1.y); o[6]=f2b(v1.z); o[7]=f2b(v1.w);
    *reinterpret_cast<u16x8v*>(hb + i) = o;
}

// ---------------------------------------------------------------------------
// cvt_wT: W[256][512] f32 -> WbT[512][256] bf16, plus WaT[16][256] f32
// (WaT[c][k] = sum_f W[k][h*64+f] * a[h][sd*64+f], c = sd*8+h, h=blockIdx.x)
// ---------------------------------------------------------------------------
__global__ __launch_bounds__(256) void cvt_wT(const float* __restrict__ W,
                                              const float* __restrict__ avec,
                                              u16* __restrict__ WbT,
                                              float* __restrict__ WaT) {
    __shared__ float T[64][65];
    const int hh = blockIdx.x;                 // head (64-col tile)
    const int n0 = hh * 64, k0 = blockIdx.y * 64;
    const int t = threadIdx.x;
    const int r4 = t >> 6, c = t & 63;
    #pragma unroll
    for (int p = 0; p < 16; ++p) {
        const int r = p * 4 + r4;
        T[r][c] = W[(size_t)(k0 + r) * NH + n0 + c];
    }
    __syncthreads();
    #pragma unroll
    for (int p = 0; p < 16; ++p) {
        const int r = p * 4 + r4;
        WbT[(size_t)(n0 + r) * FIN + k0 + c] = f2b(T[c][r]);
    }
    if (t < 128) {
        const int kl = t & 63, sd = t >> 6;
        float s = 0.f;
        #pragma unroll
        for (int f = 0; f < 64; ++f)
            s += T[kl][f] * avec[hh * 128 + sd * 64 + f];
        WaT[(sd * 8 + hh) * FIN + k0 + kl] = s;
    }
}

// ---------------------------------------------------------------------------
// calc_e2 (exact f32): wave per row i; e_src/e_dst = h[i,:] @ WaT[c,:]
// lane = (c = lane&15, kg = lane>>4)
// ---------------------------------------------------------------------------
__global__ __launch_bounds__(256) void calc_e2(const float* __restrict__ h,
                                               const float* __restrict__ WaT,
                                               float* __restrict__ esrc,
                                               float* __restrict__ edst) {
    const int t = threadIdx.x, wv = t >> 6, lane = t & 63;
    const int c = lane & 15, kg = lane >> 4;
    const int gi = blockIdx.x * 4 + wv;        // b*NN + i
    const float* hr = h   + (size_t)gi * FIN + kg * 64;
    const float* wr = WaT + (size_t)c  * FIN + kg * 64;
    float s = 0.f;
    #pragma unroll
    for (int q = 0; q < 16; ++q) {
        const float4 hv = *reinterpret_cast<const float4*>(hr + q * 4);
        const float4 wv4 = *reinterpret_cast<const float4*>(wr + q * 4);
        s += hv.x*wv4.x + hv.y*wv4.y + hv.z*wv4.z + hv.w*wv4.w;
    }
    s += __shfl_xor(s, 16);
    s += __shfl_xor(s, 32);
    if (lane < 16) {
        const int b = gi >> 10, i = gi & (NN - 1);
        if (c < 8) esrc[(size_t)(b * 8 + c) * NN + i] = s;
        else       edst[(size_t)(b * 8 + (c - 8)) * NN + i] = s;
    }
}

// ---------------------------------------------------------------------------
// pack_adj: adjacency -> bitmask, 4 elems/lane (int4) + shuffle-assemble
// ---------------------------------------------------------------------------
__global__ __launch_bounds__(256) void pack_adj(const int* __restrict__ adj,
                                                u32* __restrict__ bits) {
    const int lane = threadIdx.x & 63;
    const size_t e0 = ((size_t)blockIdx.x * 256 + threadIdx.x) * 4;
    const int4 v = *reinterpret_cast<const int4*>(adj + e0);
    u32 x = (v.x ? 1u : 0u) | (v.y ? 2u : 0u) | (v.z ? 4u : 0u) | (v.w ? 8u : 0u);
    {   const u32 r = (u32)__shfl_xor((int)x, 1);
        const int sh = (lane & 1) * 4;  x = (x << sh) | (r << (4 - sh)); }
    {   const u32 r = (u32)__shfl_xor((int)x, 2);
        const int sh = (lane & 2) * 4;  x = (x << sh) | (r << (8 - sh)); }
    {   const u32 r = (u32)__shfl_xor((int)x, 4);
        const int sh = (lane & 4) * 4;  x = (x << sh) | (r << (16 - sh)); }
    if ((lane & 7) == 0) bits[e0 >> 5] = x;
}

// ---------------------------------------------------------------------------
// gemm_whT: Wh = hb @ WbT^T via bf16 MFMA; WhT[bh][f][i] bf16 out via LDS
// bounce (coalesced). Block = (128 m-rows, head), 4 waves.
// ---------------------------------------------------------------------------
__global__ __launch_bounds__(256) void gemm_whT(const u16* __restrict__ hb,
                                                const u16* __restrict__ WbT,
                                                u16* __restrict__ WhT) {
    __shared__ u16 Al[2][128 * 64];
    __shared__ u16 Bl[2][64 * 64];
    const int t = threadIdx.x, wv = t >> 6, lane = t & 63;
    const int g = lane >> 4, l15 = lane & 15;
    const int m0 = blockIdx.x * 128;
    const int h  = blockIdx.y;
    const int lr = lane >> 3;
    const int sch = (lane & 7) ^ lr;

    f32x4 acc[2][4] = {};

    auto stageA = [&](int buf, int k0) {
        #pragma unroll
        for (int c = 0; c < 4; ++c) {
            const int rowb = wv * 32 + c * 8;
            gload_lds16(hb + (size_t)(m0 + rowb + lr) * FIN + k0 + sch * 8,
                        &Al[buf][rowb * 64]);
        }
    };
    auto stageB = [&](int buf, int k0) {
        #pragma unroll
        for (int c = 0; c < 2; ++c) {
            const int rowb = wv * 16 + c * 8;
            gload_lds16(WbT + (size_t)(h * 64 + rowb + lr) * FIN + k0 + sch * 8,
                        &Bl[buf][rowb * 64]);
        }
    };

    stageA(0, 0); stageB(0, 0);
    __syncthreads();
    for (int kt = 0; kt < 4; ++kt) {
        const int buf = kt & 1;
        if (kt < 3) { stageA(buf ^ 1, (kt + 1) * 64); stageB(buf ^ 1, (kt + 1) * 64); }
        #pragma unroll
        for (int ks = 0; ks < 2; ++ks) {
            const int ch = (ks * 4 + g) ^ (l15 & 7);
            bf16x8 afr[2];
            #pragma unroll
            for (int mf = 0; mf < 2; ++mf)
                afr[mf] = *reinterpret_cast<const bf16x8*>(
                    &Al[buf][(wv * 32 + mf * 16 + l15) * 64 + ch * 8]);
            #pragma unroll
            for (int n = 0; n < 4; ++n) {
                const bf16x8 bfr = *reinterpret_cast<const bf16x8*>(
                    &Bl[buf][(n * 16 + l15) * 64 + ch * 8]);
                acc[0][n] = __builtin_amdgcn_mfma_f32_16x16x32_bf16(afr[0], bfr, acc[0][n], 0, 0, 0);
                acc[1][n] = __builtin_amdgcn_mfma_f32_16x16x32_bf16(afr[1], bfr, acc[1][n], 0, 0, 0);
            }
        }
        __syncthreads();
    }

    // epilogue: acc -> LDS [64 f][132 i] u16 -> coalesced global stores
    u16* scr = &Al[0][0];                  // 64*132 = 8448 u16, fits
    #pragma unroll
    for (int mf = 0; mf < 2; ++mf) {
        #pragma unroll
        for (int n = 0; n < 4; ++n) {
            u16x4v pk;
            #pragma unroll
            for (int r = 0; r < 4; ++r) pk[r] = f2b(acc[mf][n][r]);
            const int fr = n * 16 + l15;
            const int ic = wv * 32 + mf * 16 + g * 4;
            *reinterpret_cast<u16x4v*>(&scr[fr * 132 + ic]) = pk;
        }
    }
    __syncthreads();
    const int bh = (m0 >> 10) * HEADS + h;
    const int il0 = m0 & (NN - 1);
    #pragma unroll
    for (int pass = 0; pass < 8; ++pass) {
        const int f  = pass * 8 + (t >> 5);
        const int ir = (t & 31) * 4;
        const u16x4v v = *reinterpret_cast<const u16x4v*>(&scr[f * 132 + ir]);
        *reinterpret_cast<u16x4v*>(&WhT[((size_t)bh * 64 + f) * NN + il0 + ir]) = v;
    }
}

// ---------------------------------------------------------------------------
// attn_pv: out = softmax(mask(lrelu(e_src+e_dst))) @ Wh, fused denominator.
// Block = (64 i, head, b), 4 waves. edst row + bit rows + Wh tiles in LDS.
// Fully-unrolled 16-tile loop; all inner reads are imm-offset ds_reads.
// ---------------------------------------------------------------------------
__global__ __launch_bounds__(256) void attn_pv(const u32* __restrict__ bits,
                                               const u16* __restrict__ WhT,
                                               const float* __restrict__ esrc,
                                               const float* __restrict__ edst,
                                               float* __restrict__ out) {
    // LDS map (bytes): [0,16384) Bs[2][4096]u16 | [16384,20480) ed f32 |
    //                  [20480,28672) bit rows u32
    __shared__ u16 lds[(16384 + 4096 + 8192) / 2];
    u16* Bs = lds;
    char* ldsb = (char*)lds;

    const int t = threadIdx.x, wv = t >> 6, lane = t & 63;
    const int g = lane >> 4, l15 = lane & 15;
    const int lr = lane >> 3, sch = (lane & 7) ^ lr;

    // chunked XCD swizzle: 128 consecutive logical blocks (8 full bh slices)
    // per XCD for L2 reuse of WhT
    const int lid = (blockIdx.x & 7) * 128 + (blockIdx.x >> 3);
    const int it = lid & 15, h = (lid >> 4) & 7, b = lid >> 7;
    const int i0 = it * 64;
    const int bh = b * HEADS + h;

    const int rowl = wv * 16 + l15;
    const int rowi = i0 + rowl;
    const float es = esrc[(size_t)bh * NN + rowi];
    const u16* whb = WhT + (size_t)bh * 64 * NN;

    auto stageB = [&](int buf, int j0) {
        #pragma unroll
        for (int c = 0; c < 2; ++c) {
            const int fb = wv * 16 + c * 8;
            gload_lds16(whb + (size_t)(fb + lr) * NN + j0 + sch * 8,
                        Bs + buf * 4096 + fb * 64);
        }
    };
    {
        const float* edr = edst + (size_t)bh * NN;
        gload_lds16(edr + wv * 256 + lane * 4, (float*)(ldsb + 16384) + wv * 256);
        const u32* bsrc = bits + (size_t)(b * NN + i0) * 32;
        gload_lds16(bsrc + (wv * 2 + 0) * 256 + lane * 4, (u32*)(ldsb + 20480) + (wv * 2 + 0) * 256);
        gload_lds16(bsrc + (wv * 2 + 1) * 256 + lane * 4, (u32*)(ldsb + 20480) + (wv * 2 + 1) * 256);
        stageB(0, 0);
    }
    __syncthreads();

    // hoisted per-lane LDS byte bases (all inner offsets are immediates)
    const int bsB[2] = { l15 * 128 + ((0 + g) ^ (l15 & 7)) * 16,
                         l15 * 128 + ((4 + g) ^ (l15 & 7)) * 16 };
    const int edB = 16384 + g * 32;
    const int bwB = 20480 + rowl * 128;

    f32x4 acc[4] = {};
    float lrun = 0.f;

    #pragma unroll
    for (int tt = 0; tt < 16; ++tt) {
        const int buf = tt & 1;
        if (tt < 15) stageB(buf ^ 1, (tt + 1) * 64);
        #pragma unroll
        for (int ks = 0; ks < 2; ++ks) {
            const float4 e0 = *(const float4*)(ldsb + edB + tt * 256 + ks * 128);
            const float4 e1 = *(const float4*)(ldsb + edB + tt * 256 + ks * 128 + 16);
            const u32 word = *(const u32*)(ldsb + bwB + (tt * 2 + ks) * 4);
            const u32 byte_ = (word >> (8 * g)) & 0xffu;
            float ps[8];
            #pragma unroll
            for (int q = 0; q < 8; ++q) {
                float s = es + ((q < 4) ? (&e0.x)[q] : (&e1.x)[q - 4]);
                s = fmaxf(s, ALPHA * s);                 // leaky relu
                s = ((byte_ >> q) & 1u) ? s : -1e30f;    // mask -> exp = 0
                ps[q] = __expf(s);                       // native v_exp
                lrun += ps[q];
            }
            union { u32 u[4]; bf16x8 v; } af;
            #pragma unroll
            for (int qp = 0; qp < 4; ++qp)
                af.u[qp] = ((u32)f2b(ps[2 * qp + 1]) << 16) | f2b(ps[2 * qp]);
            const int bsb = bsB[ks] + buf * 8192;
            #pragma unroll
            for (int n = 0; n < 4; ++n) {
                const bf16x8 bfr = *(const bf16x8*)(ldsb + bsb + n * 2048);
                acc[n] = __builtin_amdgcn_mfma_f32_16x16x32_bf16(af.v, bfr, acc[n], 0, 0, 0);
            }
        }
        if (tt < 15) __syncthreads();
    }

    // denominator: combine the 4 g-slices per row
    lrun += __shfl_xor(lrun, 16);
    lrun += __shfl_xor(lrun, 32);
    float inv[4];
    #pragma unroll
    for (int r = 0; r < 4; ++r) inv[r] = 1.0f / __shfl(lrun, g * 4 + r);
    #pragma unroll
    for (int n = 0; n < 4; ++n) {
        #pragma unroll
        for (int r = 0; r < 4; ++r) {
            const int io = i0 + wv * 16 + g * 4 + r;
            out[(size_t)(b * NN + io) * NH + h * 64 + n * 16 + l15] = acc[n][r] * inv[r];
        }
    }
}

// ---------------------------------------------------------------------------
extern "C" void kernel_launch(void* const* d_in, const int* in_sizes, int n_in,
                              void* d_out, int out_size, void* d_ws, size_t ws_size,
                              hipStream_t stream) {
    const float* h   = (const float*)d_in[0];
    const int*   adj = (const int*)  d_in[1];
    const float* W   = (const float*)d_in[2];
    const float* a   = (const float*)d_in[3];
    float* out = (float*)d_out;

    char* p = (char*)d_ws;
    u16*   hb   = (u16*)p;   p += (size_t)BS * NN * FIN * 2;        // 4 MB
    u16*   WbT  = (u16*)p;   p += (size_t)NH * FIN * 2;             // 256 KB
    u16*   WhT  = (u16*)p;   p += (size_t)BS * HEADS * FO * NN * 2; // 8 MB
    float* WaT  = (float*)p; p += (size_t)16 * FIN * 4;             // 16 KB
    float* esrc = (float*)p; p += (size_t)BS * HEADS * NN * 4;      // 256 KB
    float* edst = (float*)p; p += (size_t)BS * HEADS * NN * 4;      // 256 KB
    u32*   bits = (u32*)p;                                          // 1 MB

    cvt_wT  <<<dim3(HEADS, FIN / 64), 256, 0, stream>>>(W, a, WbT, WaT);
    cvt_h   <<<(BS * NN * FIN) / (256 * 8), 256, 0, stream>>>(h, hb);
    calc_e2 <<<(BS * NN) / 4, 256, 0, stream>>>(h, WaT, esrc, edst);
    pack_adj<<<(BS * NN * NN) / (256 * 4), 256, 0, stream>>>(adj, bits);
    gemm_whT<<<dim3((BS * NN) / 128, HEADS), 256, 0, stream>>>(hb, WbT, WhT);
    attn_pv <<<dim3(16 * HEADS * BS), 256, 0, stream>>>(bits, WhT, esrc, edst, out);
}

// Round 5
// 80.003 us; speedup vs baseline: 1.4577x; 1.4577x over previous
//
#include <hip/hip_runtime.h>
#include <hip/hip_bf16.h>
#include <math.h>

#define BS 8
#define NN 1024
#define FIN 256
#define HEADS 8
#define FO 64
#define NH (HEADS*FO)   /* 512 */
static constexpr float ALPHA = 0.2f;

typedef short bf16x8 __attribute__((ext_vector_type(8)));
typedef float f32x4  __attribute__((ext_vector_type(4)));
typedef unsigned short u16;
typedef unsigned u32;
typedef u16 u16x4v __attribute__((ext_vector_type(4)));
typedef u16 u16x8v __attribute__((ext_vector_type(8)));

__device__ __forceinline__ u16 f2b(float x) {
    __hip_bfloat16 b = __float2bfloat16(x);
    return *reinterpret_cast<u16*>(&b);
}
__device__ __forceinline__ void gload_lds16(const void* g, void* l) {
    __builtin_amdgcn_global_load_lds(
        (const __attribute__((address_space(1))) unsigned int*)g,
        (__attribute__((address_space(3))) unsigned int*)l, 16, 0, 0);
}

// ---------------------------------------------------------------------------
// cvt_h: h f32 -> bf16
// ---------------------------------------------------------------------------
__global__ __launch_bounds__(256) void cvt_h(const float* __restrict__ h,
                                             u16* __restrict__ hb) {
    const int i = (blockIdx.x * 256 + threadIdx.x) * 8;
    const float4 v0 = *reinterpret_cast<const float4*>(h + i);
    const float4 v1 = *reinterpret_cast<const float4*>(h + i + 4);
    u16x8v o;
    o[0]=f2b(v0.x); o[1]=f2b(v0.y); o[2]=f2b(v0.z); o[3]=f2b(v0.w);
    o[4]=f2b(v1.x); o[5]=f2b(v1.y); o[6]=f2b(v1.z); o[7]=f2b(v1.w);
    *reinterpret_cast<u16x8v*>(hb + i) = o;
}

// ---------------------------------------------------------------------------
// cvt_wT: W[256][512] f32 -> WbT[512][256] bf16, plus WaT[16][256] f32
// ---------------------------------------------------------------------------
__global__ __launch_bounds__(256) void cvt_wT(const float* __restrict__ W,
                                              const float* __restrict__ avec,
                                              u16* __restrict__ WbT,
                                              float* __restrict__ WaT) {
    __shared__ float T[64][65];
    const int hh = blockIdx.x;
    const int n0 = hh * 64, k0 = blockIdx.y * 64;
    const int t = threadIdx.x;
    const int r4 = t >> 6, c = t & 63;
    #pragma unroll
    for (int p = 0; p < 16; ++p) {
        const int r = p * 4 + r4;
        T[r][c] = W[(size_t)(k0 + r) * NH + n0 + c];
    }
    __syncthreads();
    #pragma unroll
    for (int p = 0; p < 16; ++p) {
        const int r = p * 4 + r4;
        WbT[(size_t)(n0 + r) * FIN + k0 + c] = f2b(T[c][r]);
    }
    if (t < 128) {
        const int kl = t & 63, sd = t >> 6;
        float s = 0.f;
        #pragma unroll
        for (int f = 0; f < 64; ++f)
            s += T[kl][f] * avec[hh * 128 + sd * 64 + f];
        WaT[(sd * 8 + hh) * FIN + k0 + kl] = s;
    }
}

// ---------------------------------------------------------------------------
// calc_e2 (exact f32): wave per row i; e_src/e_dst = h[i,:] @ WaT[c,:]
// ---------------------------------------------------------------------------
__global__ __launch_bounds__(256) void calc_e2(const float* __restrict__ h,
                                               const float* __restrict__ WaT,
                                               float* __restrict__ esrc,
                                               float* __restrict__ edst) {
    const int t = threadIdx.x, wv = t >> 6, lane = t & 63;
    const int c = lane & 15, kg = lane >> 4;
    const int gi = blockIdx.x * 4 + wv;
    const float* hr = h   + (size_t)gi * FIN + kg * 64;
    const float* wr = WaT + (size_t)c  * FIN + kg * 64;
    float s = 0.f;
    #pragma unroll
    for (int q = 0; q < 16; ++q) {
        const float4 hv = *reinterpret_cast<const float4*>(hr + q * 4);
        const float4 wv4 = *reinterpret_cast<const float4*>(wr + q * 4);
        s += hv.x*wv4.x + hv.y*wv4.y + hv.z*wv4.z + hv.w*wv4.w;
    }
    s += __shfl_xor(s, 16);
    s += __shfl_xor(s, 32);
    if (lane < 16) {
        const int b = gi >> 10, i = gi & (NN - 1);
        if (c < 8) esrc[(size_t)(b * 8 + c) * NN + i] = s;
        else       edst[(size_t)(b * 8 + (c - 8)) * NN + i] = s;
    }
}

// ---------------------------------------------------------------------------
// pack_adj: adjacency -> bitmask, 4 elems/lane (int4) + shuffle-assemble
// ---------------------------------------------------------------------------
__global__ __launch_bounds__(256) void pack_adj(const int* __restrict__ adj,
                                                u32* __restrict__ bits) {
    const int lane = threadIdx.x & 63;
    const size_t e0 = ((size_t)blockIdx.x * 256 + threadIdx.x) * 4;
    const int4 v = *reinterpret_cast<const int4*>(adj + e0);
    u32 x = (v.x ? 1u : 0u) | (v.y ? 2u : 0u) | (v.z ? 4u : 0u) | (v.w ? 8u : 0u);
    {   const u32 r = (u32)__shfl_xor((int)x, 1);
        const int sh = (lane & 1) * 4;  x = (x << sh) | (r << (4 - sh)); }
    {   const u32 r = (u32)__shfl_xor((int)x, 2);
        const int sh = (lane & 2) * 4;  x = (x << sh) | (r << (8 - sh)); }
    {   const u32 r = (u32)__shfl_xor((int)x, 4);
        const int sh = (lane & 4) * 4;  x = (x << sh) | (r << (16 - sh)); }
    if ((lane & 7) == 0) bits[e0 >> 5] = x;
}

// ---------------------------------------------------------------------------
// gemm_whT: Wh = hb @ WbT^T via bf16 MFMA; WhT[bh][f][i] bf16 out via LDS
// bounce. 1D grid 512, XCD-chunked: each XCD gets 8 m-tiles x 8 heads
// so the A panel is L2-resident per XCD.
// ---------------------------------------------------------------------------
__global__ __launch_bounds__(256) void gemm_whT(const u16* __restrict__ hb,
                                                const u16* __restrict__ WbT,
                                                u16* __restrict__ WhT) {
    __shared__ u16 Al[2][128 * 64];
    __shared__ u16 Bl[2][64 * 64];
    const int t = threadIdx.x, wv = t >> 6, lane = t & 63;
    const int g = lane >> 4, l15 = lane & 15;
    const int lid = (blockIdx.x & 7) * 64 + (blockIdx.x >> 3);
    const int m0 = (lid >> 3) * 128;
    const int h  = lid & 7;
    const int lr = lane >> 3;
    const int sch = (lane & 7) ^ lr;

    f32x4 acc[2][4] = {};

    auto stageA = [&](int buf, int k0) {
        #pragma unroll
        for (int c = 0; c < 4; ++c) {
            const int rowb = wv * 32 + c * 8;
            gload_lds16(hb + (size_t)(m0 + rowb + lr) * FIN + k0 + sch * 8,
                        &Al[buf][rowb * 64]);
        }
    };
    auto stageB = [&](int buf, int k0) {
        #pragma unroll
        for (int c = 0; c < 2; ++c) {
            const int rowb = wv * 16 + c * 8;
            gload_lds16(WbT + (size_t)(h * 64 + rowb + lr) * FIN + k0 + sch * 8,
                        &Bl[buf][rowb * 64]);
        }
    };

    stageA(0, 0); stageB(0, 0);
    __syncthreads();
    for (int kt = 0; kt < 4; ++kt) {
        const int buf = kt & 1;
        if (kt < 3) { stageA(buf ^ 1, (kt + 1) * 64); stageB(buf ^ 1, (kt + 1) * 64); }
        #pragma unroll
        for (int ks = 0; ks < 2; ++ks) {
            const int ch = (ks * 4 + g) ^ (l15 & 7);
            bf16x8 afr[2];
            #pragma unroll
            for (int mf = 0; mf < 2; ++mf)
                afr[mf] = *reinterpret_cast<const bf16x8*>(
                    &Al[buf][(wv * 32 + mf * 16 + l15) * 64 + ch * 8]);
            #pragma unroll
            for (int n = 0; n < 4; ++n) {
                const bf16x8 bfr = *reinterpret_cast<const bf16x8*>(
                    &Bl[buf][(n * 16 + l15) * 64 + ch * 8]);
                acc[0][n] = __builtin_amdgcn_mfma_f32_16x16x32_bf16(afr[0], bfr, acc[0][n], 0, 0, 0);
                acc[1][n] = __builtin_amdgcn_mfma_f32_16x16x32_bf16(afr[1], bfr, acc[1][n], 0, 0, 0);
            }
        }
        __syncthreads();
    }

    // epilogue: acc -> LDS [64 f][132 i] u16 -> coalesced global stores
    u16* scr = &Al[0][0];
    #pragma unroll
    for (int mf = 0; mf < 2; ++mf) {
        #pragma unroll
        for (int n = 0; n < 4; ++n) {
            u16x4v pk;
            #pragma unroll
            for (int r = 0; r < 4; ++r) pk[r] = f2b(acc[mf][n][r]);
            const int fr = n * 16 + l15;
            const int ic = wv * 32 + mf * 16 + g * 4;
            *reinterpret_cast<u16x4v*>(&scr[fr * 132 + ic]) = pk;
        }
    }
    __syncthreads();
    const int bh = (m0 >> 10) * HEADS + h;
    const int il0 = m0 & (NN - 1);
    #pragma unroll
    for (int pass = 0; pass < 8; ++pass) {
        const int f  = pass * 8 + (t >> 5);
        const int ir = (t & 31) * 4;
        const u16x4v v = *reinterpret_cast<const u16x4v*>(&scr[f * 132 + ir]);
        *reinterpret_cast<u16x4v*>(&WhT[((size_t)bh * 64 + f) * NN + il0 + ir]) = v;
    }
}

// ---------------------------------------------------------------------------
// attn_pv: out = softmax(mask(lrelu(e_src+e_dst))) @ Wh, fused denominator.
// Block = (64 i, head, b), 4 waves, rolled 16-tile loop (low VGPR).
// LDS: Bs dbuf | edst row | bitsT[word][row] (transposed: conflict-free).
// ---------------------------------------------------------------------------
__global__ __launch_bounds__(256, 5) void attn_pv(const u32* __restrict__ bits,
                                                  const u16* __restrict__ WhT,
                                                  const float* __restrict__ esrc,
                                                  const float* __restrict__ edst,
                                                  float* __restrict__ out) {
    // LDS map (bytes): [0,16384) Bs[2][4096]u16 | [16384,20480) ed f32[1024]
    //                  | [20480,28672) bitsT u32[32][64]
    __shared__ u16 lds[(16384 + 4096 + 8192) / 2];
    u16* Bs = lds;
    char* ldsb = (char*)lds;

    const int t = threadIdx.x, wv = t >> 6, lane = t & 63;
    const int g = lane >> 4, l15 = lane & 15;
    const int lr = lane >> 3, sch = (lane & 7) ^ lr;

    // chunked XCD swizzle: 128 consecutive logical blocks per XCD
    const int lid = (blockIdx.x & 7) * 128 + (blockIdx.x >> 3);
    const int it = lid & 15, h = (lid >> 4) & 7, b = lid >> 7;
    const int i0 = it * 64;
    const int bh = b * HEADS + h;

    const int rowl = wv * 16 + l15;
    const int rowi = i0 + rowl;
    const float es = esrc[(size_t)bh * NN + rowi];
    const u16* whb = WhT + (size_t)bh * 64 * NN;

    auto stageB = [&](int buf, int j0) {
        #pragma unroll
        for (int c = 0; c < 2; ++c) {
            const int fb = wv * 16 + c * 8;
            gload_lds16(whb + (size_t)(fb + lr) * NN + j0 + sch * 8,
                        Bs + buf * 4096 + fb * 64);
        }
    };

    // --- one-time staging ---
    {
        const float* edr = edst + (size_t)bh * NN;
        gload_lds16(edr + wv * 256 + lane * 4, ldsb + 16384 + wv * 1024);
        stageB(0, 0);
    }
    {   // bitsT transpose via registers: thread t -> row r=t>>2, words wg*8..+7
        const int r = t >> 2, wg = t & 3;
        const u32* bsrc = bits + (size_t)(b * NN + i0 + r) * 32 + wg * 8;
        const int4 w0 = *reinterpret_cast<const int4*>(bsrc);
        const int4 w1 = *reinterpret_cast<const int4*>(bsrc + 4);
        u32* bt = (u32*)(ldsb + 20480);
        #pragma unroll
        for (int q = 0; q < 8; ++q) {
            const u32 val = (q < 4) ? ((const u32*)&w0)[q] : ((const u32*)&w1)[q - 4];
            bt[(wg * 8 + q) * 64 + r] = val;
        }
    }
    __syncthreads();

    // hoisted per-lane LDS byte bases
    const int bsB[2] = { l15 * 128 + ((0 + g) ^ (l15 & 7)) * 16,
                         l15 * 128 + ((4 + g) ^ (l15 & 7)) * 16 };
    const int edB = 16384 + g * 32;
    const int btB = 20480 + rowl * 4;

    f32x4 acc[4] = {};
    float lrun = 0.f;

    for (int tt = 0; tt < 16; ++tt) {
        const int buf = tt & 1;
        if (tt < 15) stageB(buf ^ 1, (tt + 1) * 64);
        #pragma unroll
        for (int ks = 0; ks < 2; ++ks) {
            const float4 e0 = *(const float4*)(ldsb + edB + tt * 256 + ks * 128);
            const float4 e1 = *(const float4*)(ldsb + edB + tt * 256 + ks * 128 + 16);
            const u32 word = *(const u32*)(ldsb + btB + (tt * 2 + ks) * 256);
            const u32 byte_ = (word >> (8 * g)) & 0xffu;
            float ps[8];
            #pragma unroll
            for (int q = 0; q < 8; ++q) {
                float s = es + ((q < 4) ? (&e0.x)[q] : (&e1.x)[q - 4]);
                s = fmaxf(s, ALPHA * s);                 // leaky relu
                s = ((byte_ >> q) & 1u) ? s : -1e30f;    // mask
                ps[q] = __expf(s);                       // native v_exp
            }
            lrun += ((ps[0] + ps[1]) + (ps[2] + ps[3]))
                  + ((ps[4] + ps[5]) + (ps[6] + ps[7]));
            union { u32 u[4]; bf16x8 v; } af;
            #pragma unroll
            for (int qp = 0; qp < 4; ++qp)
                af.u[qp] = ((u32)f2b(ps[2 * qp + 1]) << 16) | f2b(ps[2 * qp]);
            const u16* bsb = (const u16*)(ldsb + bsB[ks]) + buf * 4096;
            #pragma unroll
            for (int n = 0; n < 4; ++n) {
                const bf16x8 bfr = *(const bf16x8*)(bsb + n * 1024);
                acc[n] = __builtin_amdgcn_mfma_f32_16x16x32_bf16(af.v, bfr, acc[n], 0, 0, 0);
            }
        }
        if (tt < 15) __syncthreads();
    }

    // denominator: combine the 4 g-slices per row
    lrun += __shfl_xor(lrun, 16);
    lrun += __shfl_xor(lrun, 32);
    float inv[4];
    #pragma unroll
    for (int r = 0; r < 4; ++r) inv[r] = 1.0f / __shfl(lrun, g * 4 + r);
    #pragma unroll
    for (int n = 0; n < 4; ++n) {
        #pragma unroll
        for (int r = 0; r < 4; ++r) {
            const int io = i0 + wv * 16 + g * 4 + r;
            out[(size_t)(b * NN + io) * NH + h * 64 + n * 16 + l15] = acc[n][r] * inv[r];
        }
    }
}

// ---------------------------------------------------------------------------
extern "C" void kernel_launch(void* const* d_in, const int* in_sizes, int n_in,
                              void* d_out, int out_size, void* d_ws, size_t ws_size,
                              hipStream_t stream) {
    const float* h   = (const float*)d_in[0];
    const int*   adj = (const int*)  d_in[1];
    const float* W   = (const float*)d_in[2];
    const float* a   = (const float*)d_in[3];
    float* out = (float*)d_out;

    char* p = (char*)d_ws;
    u16*   hb   = (u16*)p;   p += (size_t)BS * NN * FIN * 2;        // 4 MB
    u16*   WbT  = (u16*)p;   p += (size_t)NH * FIN * 2;             // 256 KB
    u16*   WhT  = (u16*)p;   p += (size_t)BS * HEADS * FO * NN * 2; // 8 MB
    float* WaT  = (float*)p; p += (size_t)16 * FIN * 4;             // 16 KB
    float* esrc = (float*)p; p += (size_t)BS * HEADS * NN * 4;      // 256 KB
    float* edst = (float*)p; p += (size_t)BS * HEADS * NN * 4;      // 256 KB
    u32*   bits = (u32*)p;                                          // 1 MB

    cvt_wT  <<<dim3(HEADS, FIN / 64), 256, 0, stream>>>(W, a, WbT, WaT);
    cvt_h   <<<(BS * NN * FIN) / (256 * 8), 256, 0, stream>>>(h, hb);
    calc_e2 <<<(BS * NN) / 4, 256, 0, stream>>>(h, WaT, esrc, edst);
    pack_adj<<<(BS * NN * NN) / (256 * 4), 256, 0, stream>>>(adj, bits);
    gemm_whT<<<512, 256, 0, stream>>>(hb, WbT, WhT);
    attn_pv <<<dim3(16 * HEADS * BS), 256, 0, stream>>>(bits, WhT, esrc, edst, out);
}